// Round 3
// baseline (4676.877 us; speedup 1.0000x reference)
//
#include <hip/hip_runtime.h>

// LSTM B=64, S=512, D=H=512 — persistent kernel.
// Topology (round-1, best known): 128 WGs = 4 batch-groups (16 rows) x 32
// h-slices (16 h-cols = 64 gate cols). Groups are CONTIGUOUS bid ranges ->
// spread across all 8 XCDs (round-2 taught us concentrating a group on one
// XCD serializes its LLC traffic).
// Sync (new): per-producer flag array, 128B apart. Producers: one release
// fence + parallel relaxed flag stores (no RMW serialization). Consumers:
// 32-lane parallel relaxed poll + one acquire fence. Removes the ~32x
// serialized atomicAdd on one line that dominated round 1's 5.6 us/step.

#define NG   4
#define GR   16
#define NS   32
#define SC   16
#define DIM  512
#define HID  512
#define SEQ  512
#define NTHR 256
#define NWG  (NG*NS)

#define AOFF 0
#define BOFF (GR*1024)                 // A region: 16 rows x 512 bf16 = 16 KB
#define LDS_BYTES (BOFF + 64*2048)     // + B region 128 KB = 147456

#define WS_FLAG_BYTES 16384            // 4 groups x 32 flags x 128 B
#define HBUF_ELEMS   (2*NG*GR*HID)     // 2 parities x 64 rows x 512
#define WS_NEED      (WS_FLAG_BYTES + HBUF_ELEMS*2)

typedef float f32x4  __attribute__((ext_vector_type(4)));
typedef short bf16x8 __attribute__((ext_vector_type(8)));

__device__ __forceinline__ unsigned short f2bf(float f){
  union { float f; unsigned u; } v; v.f = f;
  unsigned r = v.u + 0x7fffu + ((v.u >> 16) & 1u);   // RNE
  return (unsigned short)(r >> 16);
}
__device__ __forceinline__ float sigm(float x){ return 1.0f/(1.0f + __expf(-x)); }
__device__ __forceinline__ float tanh_f(float x){
  float e = __expf(-2.0f * fabsf(x));
  float t = (1.0f - e)/(1.0f + e);
  return x < 0.0f ? -t : t;
}

__global__ void zero_ws_kernel(uint4* p, int n4){
  int i = blockIdx.x*blockDim.x + threadIdx.x;
  uint4 z; z.x=0u; z.y=0u; z.z=0u; z.w=0u;
  if (i < n4) p[i] = z;
}

__global__ __launch_bounds__(NTHR, 1) void lstm_persistent(
  const float* __restrict__ x,
  const float* __restrict__ W0, const float* __restrict__ W1,
  const float* __restrict__ W2, const float* __restrict__ W3,
  const float* __restrict__ U0, const float* __restrict__ U1,
  const float* __restrict__ U2, const float* __restrict__ U3,
  const float* __restrict__ b0, const float* __restrict__ b1,
  const float* __restrict__ b2, const float* __restrict__ b3,
  float* __restrict__ out,
  unsigned* __restrict__ flags,
  unsigned short* __restrict__ hbuf)
{
  __shared__ __align__(16) char smem[LDS_BYTES];
  const int tid = threadIdx.x;
  const int bid = blockIdx.x;
  const int g = bid >> 5;       // batch group 0..3 (contiguous bids -> XCD spread)
  const int s = bid & 31;       // h-slice 0..31 (h cols 16s..16s+15)
  const int w = tid >> 6;       // wave = gate (i,f,o,c)
  const int l = tid & 63;

  // ---- one-time: stage B = [W;U] slice into LDS, COALESCED global reads ----
  // thread: q = tid&3 (16B chunk of the slice's 64B row segment), kk = tid>>2
  {
    const int q  = tid & 3;
    const int kk = tid >> 2;
    for (int gate = 0; gate < 4; ++gate){
      const float* Wsrc = (gate==0)?W0:(gate==1)?W1:(gate==2)?W2:W3;
      const float* Usrc = (gate==0)?U0:(gate==1)?U1:(gate==2)?U2:U3;
      #pragma unroll
      for (int kb = 0; kb < 16; ++kb){
        const int k = kb*64 + kk;                       // 0..1023 over [W;U]
        const float* p = (k < DIM)
          ? (Wsrc + (size_t)k*HID + s*SC + q*4)
          : (Usrc + (size_t)(k-DIM)*HID + s*SC + q*4);
        f32x4 v = *(const f32x4*)p;
        #pragma unroll
        for (int j = 0; j < 4; ++j){
          const int c = gate*16 + q*4 + j;              // local gate col 0..63
          const unsigned byte = ((unsigned)(k*2)) ^ ((unsigned)((c&7)<<4));
          *(unsigned short*)(&smem[BOFF + c*2048] + byte) = f2bf(v[j]);
        }
      }
    }
  }

  // elementwise mapping: thread -> (row er 0..15, col ec 0..15)
  const int er = tid >> 4;
  const int ec = tid & 15;
  const int ecol = s*SC + ec;
  const float bi = b0[ecol], bff = b1[ecol], bo = b2[ecol], bc = b3[ecol];
  float cstate = 0.0f, hout = 0.0f;

  // MFMA fragment constants
  const int arow = l & 15;
  const int qh   = l >> 4;
  const unsigned swz = (unsigned)((arow & 7) << 4);     // (w*16+arow)&7 == arow&7
  const char* Abase = &smem[AOFF + arow*1024];
  const char* Bbase = &smem[BOFF + (w*16 + arow)*2048];
  float* gatesLds = (float*)&smem[AOFF];                // alias, post-GEMM only

  // staging mapping: thread -> (row sr 0..15, 32-elem chunk sdb 0..15)
  const int sr  = tid >> 4;
  const int sdb = tid & 15;
  const unsigned swzS = (unsigned)((sr & 7) << 4);
  char* Arow = &smem[AOFF + sr*1024];

  unsigned* gflags = flags + g*1024;    // 32 flags, 32 uints (128 B) apart

  __syncthreads();

#define GEMM_STEP(QA, QB, ACC) do { \
    bf16x8 a_ = *(const bf16x8*)(Abase + (((unsigned)((QA)*64 + qh*16)) ^ swz)); \
    bf16x8 b_ = *(const bf16x8*)(Bbase + (((unsigned)((QB)*64 + qh*16)) ^ swz)); \
    ACC = __builtin_amdgcn_mfma_f32_16x16x32_bf16(a_, b_, ACC, 0, 0, 0); \
  } while(0)

  for (int t = 0; t < SEQ; ++t){
    // 1) stage x[g-rows, t, :] -> A (fp32->bf16): row sr, 32 floats/thread
    {
      const float* xp = x + ((size_t)(g*GR + sr)*SEQ + (size_t)t)*DIM + sdb*32;
      #pragma unroll
      for (int j = 0; j < 4; ++j){
        f32x4 u = *(const f32x4*)(xp + j*8);
        f32x4 v = *(const f32x4*)(xp + j*8 + 4);
        bf16x8 o8;
        o8[0]=(short)f2bf(u[0]); o8[1]=(short)f2bf(u[1]);
        o8[2]=(short)f2bf(u[2]); o8[3]=(short)f2bf(u[3]);
        o8[4]=(short)f2bf(v[0]); o8[5]=(short)f2bf(v[1]);
        o8[6]=(short)f2bf(v[2]); o8[7]=(short)f2bf(v[3]);
        *(bf16x8*)(Arow + (((unsigned)(sdb*64 + j*16)) ^ swzS)) = o8;
      }
    }
    __syncthreads();                                   // bar1

    f32x4 acc0 = {0.f,0.f,0.f,0.f}, acc1 = {0.f,0.f,0.f,0.f};
    f32x4 acc2 = {0.f,0.f,0.f,0.f}, acc3 = {0.f,0.f,0.f,0.f};

    // 2) x-half GEMM (B rows 0..511 = W), overlapped with the flag wait window
    #pragma unroll
    for (int q4 = 0; q4 < 4; ++q4){
      GEMM_STEP(q4*4+0, q4*4+0, acc0);
      GEMM_STEP(q4*4+1, q4*4+1, acc1);
      GEMM_STEP(q4*4+2, q4*4+2, acc2);
      GEMM_STEP(q4*4+3, q4*4+3, acc3);
    }

    // 3) wait: 32 lanes poll 32 per-producer flags in parallel (no RMW)
    if (t > 0 && tid < 32){
      const unsigned* fp = &gflags[tid*32];
      while (__hip_atomic_load(fp, __ATOMIC_RELAXED, __HIP_MEMORY_SCOPE_AGENT)
             < (unsigned)t) { /* LLC load latency self-throttles */ }
    }
    __syncthreads();                                   // bar2
    if (t > 0)
      __builtin_amdgcn_fence(__ATOMIC_ACQUIRE, "agent");

    // 4) stage h_{t-1} -> A (bf16 passthrough)
    {
      const unsigned short* hsrc =
        hbuf + ((size_t)((t&1)*NG + g)*GR + sr)*HID + sdb*32;
      #pragma unroll
      for (int j = 0; j < 4; ++j){
        bf16x8 hv = *(const bf16x8*)(hsrc + j*8);
        *(bf16x8*)(Arow + (((unsigned)(sdb*64 + j*16)) ^ swzS)) = hv;
      }
    }
    __syncthreads();                                   // bar3

    // 5) h-half GEMM (B rows 512..1023 = U)
    #pragma unroll
    for (int q4 = 0; q4 < 4; ++q4){
      GEMM_STEP(q4*4+0, q4*4+16, acc0);
      GEMM_STEP(q4*4+1, q4*4+17, acc1);
      GEMM_STEP(q4*4+2, q4*4+18, acc2);
      GEMM_STEP(q4*4+3, q4*4+19, acc3);
    }
    __syncthreads();                                   // bar4: A consumed

    // 6) gate exchange (C/D: col=l&15, row=4*qh+rr)
    f32x4 accs = (acc0 + acc1) + (acc2 + acc3);
    #pragma unroll
    for (int rr = 0; rr < 4; ++rr)
      gatesLds[(qh*4 + rr)*64 + w*16 + arow] = accs[rr];
    __syncthreads();                                   // bar5

    // 7) elementwise LSTM cell, fp32 state
    {
      float gi = gatesLds[er*64 +  0 + ec] + bi;
      float gf = gatesLds[er*64 + 16 + ec] + bff;
      float go = gatesLds[er*64 + 32 + ec] + bo;
      float gc = gatesLds[er*64 + 48 + ec] + bc;
      float ig = sigm(gi), fg = sigm(gf), og = sigm(go), ct = tanh_f(gc);
      cstate = fg*cstate + ig*ct;
      hout = og * tanh_f(cstate);
      hbuf[((size_t)(((t+1)&1)*NG + g)*GR + er)*HID + s*SC + ec] = f2bf(hout);
    }
    __syncthreads();                                   // bar6: h stores drained

    // 8) release: one fence, then parallel per-producer flag store (no RMW)
    if (tid == 0){
      __builtin_amdgcn_fence(__ATOMIC_RELEASE, "agent");
      __hip_atomic_store(&gflags[s*32], (unsigned)(t+1),
                         __ATOMIC_RELAXED, __HIP_MEMORY_SCOPE_AGENT);
    }
  }

  out[(size_t)(g*GR + er)*HID + s*SC + ec] = hout;
#undef GEMM_STEP
}

extern "C" void kernel_launch(void* const* d_in, const int* in_sizes, int n_in,
                              void* d_out, int out_size, void* d_ws, size_t ws_size,
                              hipStream_t stream)
{
  (void)in_sizes; (void)n_in; (void)out_size;
  if (ws_size < (size_t)WS_NEED) return;

  const float* x  = (const float*)d_in[0];
  const float* W0 = (const float*)d_in[1];
  const float* W1 = (const float*)d_in[2];
  const float* W2 = (const float*)d_in[3];
  const float* W3 = (const float*)d_in[4];
  const float* U0 = (const float*)d_in[5];
  const float* U1 = (const float*)d_in[6];
  const float* U2 = (const float*)d_in[7];
  const float* U3 = (const float*)d_in[8];
  const float* b0 = (const float*)d_in[9];
  const float* b1 = (const float*)d_in[10];
  const float* b2 = (const float*)d_in[11];
  const float* b3 = (const float*)d_in[12];
  float* out = (float*)d_out;

  unsigned* flags = (unsigned*)d_ws;
  unsigned short* hbuf = (unsigned short*)((char*)d_ws + WS_FLAG_BYTES);

  const int n4 = WS_NEED / 16;
  zero_ws_kernel<<<dim3((n4 + 255)/256), dim3(256), 0, stream>>>((uint4*)d_ws, n4);
  lstm_persistent<<<dim3(NWG), dim3(NTHR), 0, stream>>>(
      x, W0,W1,W2,W3, U0,U1,U2,U3, b0,b1,b2,b3, out, flags, hbuf);
}

// Round 4
// 2823.833 us; speedup vs baseline: 1.6562x; 1.6562x over previous
//
#include <hip/hip_runtime.h>

// LSTM B=64, S=512, D=H=512 — persistent kernel, FENCE-FREE sync.
// Key insight (round 3 post-mortem): agent-scope release/acquire fences on
// gfx950 emit buffer_wbl2 / buffer_inv (full L2 writeback/invalidate) — every
// WG was paying that EVERY step. This version has zero fences in the hot
// loop: all cross-WG data (h, flags) moves via RELAXED agent-scope atomic
// load/store (sc1: bypass L1/L2, meet at LLC). Ordering: __syncthreads()
// drains vmcnt (h stores ack'd at LLC) before the flag store issues.
//  - 128 WGs = 4 batch-groups (16 rows, contiguous bids -> XCD-spread) x 32
//    h-slices (16 h-cols = 64 gate cols). 1 WG/CU.
//  - B = [W;U] slice (1024x64) bf16 in LDS (128 KB, swizzled, coalesced init).
//  - gates exchange in a separate 4 KB LDS region (one barrier dropped).
//  - x-staging for t+1 overlapped with the h-store drain window.

#define NG   4
#define GR   16
#define NS   32
#define SC   16
#define DIM  512
#define HID  512
#define SEQ  512
#define NTHR 256
#define NWG  (NG*NS)

#define AOFF 0
#define GOFF (GR*1024)                  // gates region: 16x64 f32 = 4 KB
#define BOFF (GOFF + 4096)
#define LDS_BYTES (BOFF + 64*2048)      // 16K A + 4K gates + 128K B = 151552

#define WS_FLAG_BYTES 16384             // 4 groups x 32 flags x 128 B
#define HBUF_UINTS   (2*NG*GR*256)      // 2 parities x 64 rows x 256 uints
#define WS_NEED      (WS_FLAG_BYTES + HBUF_UINTS*4)

typedef float f32x4  __attribute__((ext_vector_type(4)));
typedef short bf16x8 __attribute__((ext_vector_type(8)));

__device__ __forceinline__ unsigned short f2bf(float f){
  union { float f; unsigned u; } v; v.f = f;
  unsigned r = v.u + 0x7fffu + ((v.u >> 16) & 1u);   // RNE
  return (unsigned short)(r >> 16);
}
__device__ __forceinline__ float sigm(float x){ return 1.0f/(1.0f + __expf(-x)); }
__device__ __forceinline__ float tanh_f(float x){
  float e = __expf(-2.0f * fabsf(x));
  float t = (1.0f - e)/(1.0f + e);
  return x < 0.0f ? -t : t;
}

__global__ void zero_ws_kernel(uint4* p, int n4){
  int i = blockIdx.x*blockDim.x + threadIdx.x;
  uint4 z; z.x=0u; z.y=0u; z.z=0u; z.w=0u;
  if (i < n4) p[i] = z;
}

__global__ __launch_bounds__(NTHR, 1) void lstm_persistent(
  const float* __restrict__ x,
  const float* __restrict__ W0, const float* __restrict__ W1,
  const float* __restrict__ W2, const float* __restrict__ W3,
  const float* __restrict__ U0, const float* __restrict__ U1,
  const float* __restrict__ U2, const float* __restrict__ U3,
  const float* __restrict__ b0, const float* __restrict__ b1,
  const float* __restrict__ b2, const float* __restrict__ b3,
  float* __restrict__ out,
  unsigned* __restrict__ flags,
  unsigned* __restrict__ hbuf32)
{
  __shared__ __align__(16) char smem[LDS_BYTES];
  const int tid = threadIdx.x;
  const int bid = blockIdx.x;
  const int g = bid >> 5;       // batch group 0..3 (contiguous -> XCD spread)
  const int s = bid & 31;       // h-slice 0..31 (h cols 16s..16s+15)
  const int w = tid >> 6;       // wave = gate (i,f,o,c)
  const int l = tid & 63;

  // ---- one-time: stage B = [W;U] slice into LDS, coalesced reads ----
  {
    const int q  = tid & 3;
    const int kk = tid >> 2;
    for (int gate = 0; gate < 4; ++gate){
      const float* Wsrc = (gate==0)?W0:(gate==1)?W1:(gate==2)?W2:W3;
      const float* Usrc = (gate==0)?U0:(gate==1)?U1:(gate==2)?U2:U3;
      #pragma unroll
      for (int kb = 0; kb < 16; ++kb){
        const int k = kb*64 + kk;                       // 0..1023 over [W;U]
        const float* p = (k < DIM)
          ? (Wsrc + (size_t)k*HID + s*SC + q*4)
          : (Usrc + (size_t)(k-DIM)*HID + s*SC + q*4);
        f32x4 v = *(const f32x4*)p;
        #pragma unroll
        for (int j = 0; j < 4; ++j){
          const int c = gate*16 + q*4 + j;              // local gate col 0..63
          const unsigned byte = ((unsigned)(k*2)) ^ ((unsigned)((c&7)<<4));
          *(unsigned short*)(&smem[BOFF + c*2048] + byte) = f2bf(v[j]);
        }
      }
    }
  }

  // elementwise mapping: thread -> (row er 0..15, col ec 0..15)
  const int er = tid >> 4;
  const int ec = tid & 15;
  const int ecol = s*SC + ec;
  const float bi = b0[ecol], bff = b1[ecol], bo = b2[ecol], bc = b3[ecol];
  float cstate = 0.0f, hout = 0.0f;

  // MFMA fragment constants
  const int arow = l & 15;
  const int qh   = l >> 4;
  const unsigned swz = (unsigned)((arow & 7) << 4);     // (w*16+arow)&7 == arow&7
  const char* Abase = &smem[AOFF + arow*1024];
  const char* Bbase = &smem[BOFF + (w*16 + arow)*2048];
  float* gatesLds = (float*)&smem[GOFF];                // dedicated region

  // staging mapping: thread -> (row sr 0..15, 32-elem chunk sdb 0..15)
  const int sr  = tid >> 4;
  const int sdb = tid & 15;
  const unsigned swzS = (unsigned)((sr & 7) << 4);
  char* Arow = &smem[AOFF + sr*1024];

  unsigned* gflags = flags + g*1024;    // 32 flags, 128 B apart

#define STAGE_X(T) do { \
    const float* xp = x + ((size_t)(g*GR + sr)*SEQ + (size_t)(T))*DIM + sdb*32; \
    _Pragma("unroll") \
    for (int j = 0; j < 4; ++j){ \
      f32x4 u = *(const f32x4*)(xp + j*8); \
      f32x4 v = *(const f32x4*)(xp + j*8 + 4); \
      bf16x8 o8; \
      o8[0]=(short)f2bf(u[0]); o8[1]=(short)f2bf(u[1]); \
      o8[2]=(short)f2bf(u[2]); o8[3]=(short)f2bf(u[3]); \
      o8[4]=(short)f2bf(v[0]); o8[5]=(short)f2bf(v[1]); \
      o8[6]=(short)f2bf(v[2]); o8[7]=(short)f2bf(v[3]); \
      *(bf16x8*)(Arow + (((unsigned)(sdb*64 + j*16)) ^ swzS)) = o8; \
    } \
  } while(0)

#define GEMM_STEP(QA, QB, ACC) do { \
    bf16x8 a_ = *(const bf16x8*)(Abase + (((unsigned)((QA)*64 + qh*16)) ^ swz)); \
    bf16x8 b_ = *(const bf16x8*)(Bbase + (((unsigned)((QB)*64 + qh*16)) ^ swz)); \
    ACC = __builtin_amdgcn_mfma_f32_16x16x32_bf16(a_, b_, ACC, 0, 0, 0); \
  } while(0)

  // prologue: stage x_0 (bar1 at loop top makes it visible)
  STAGE_X(0);

  for (int t = 0; t < SEQ; ++t){
    __syncthreads();                                   // bar1: x_t staged

    f32x4 acc0 = {0.f,0.f,0.f,0.f}, acc1 = {0.f,0.f,0.f,0.f};
    f32x4 acc2 = {0.f,0.f,0.f,0.f}, acc3 = {0.f,0.f,0.f,0.f};

    // x-half GEMM (B rows 0..511 = W)
    #pragma unroll
    for (int q4 = 0; q4 < 4; ++q4){
      GEMM_STEP(q4*4+0, q4*4+0, acc0);
      GEMM_STEP(q4*4+1, q4*4+1, acc1);
      GEMM_STEP(q4*4+2, q4*4+2, acc2);
      GEMM_STEP(q4*4+3, q4*4+3, acc3);
    }

    // wait: 32 lanes poll 32 per-producer flags (relaxed, LLC-coherent)
    if (t > 0 && tid < 32){
      const unsigned* fp = &gflags[tid*32];
      while (__hip_atomic_load(fp, __ATOMIC_RELAXED, __HIP_MEMORY_SCOPE_AGENT)
             < (unsigned)t) { }
    }
    __syncthreads();                                   // bar2: h_{t-1} published

    // stage h_{t-1} -> A via relaxed agent loads (bypass stale L1/L2)
    {
      const unsigned* hsrc =
        hbuf32 + ((size_t)((t&1)*NG + g)*GR + sr)*256 + sdb*16;
      unsigned ld[16];
      #pragma unroll
      for (int j = 0; j < 16; ++j)
        ld[j] = __hip_atomic_load(hsrc + j, __ATOMIC_RELAXED,
                                  __HIP_MEMORY_SCOPE_AGENT);
      #pragma unroll
      for (int q = 0; q < 4; ++q){
        bf16x8 o;
        #pragma unroll
        for (int e = 0; e < 4; ++e){
          unsigned u = ld[q*4 + e];
          o[2*e]   = (short)(u & 0xffffu);
          o[2*e+1] = (short)(u >> 16);
        }
        *(bf16x8*)(Arow + (((unsigned)(sdb*64 + q*16)) ^ swzS)) = o;
      }
    }
    __syncthreads();                                   // bar3: h staged

    // h-half GEMM (B rows 512..1023 = U)
    #pragma unroll
    for (int q4 = 0; q4 < 4; ++q4){
      GEMM_STEP(q4*4+0, q4*4+16, acc0);
      GEMM_STEP(q4*4+1, q4*4+17, acc1);
      GEMM_STEP(q4*4+2, q4*4+18, acc2);
      GEMM_STEP(q4*4+3, q4*4+19, acc3);
    }

    // gate exchange into dedicated region (C/D: col=l&15, row=4*qh+rr)
    f32x4 accs = (acc0 + acc1) + (acc2 + acc3);
    #pragma unroll
    for (int rr = 0; rr < 4; ++rr)
      gatesLds[(qh*4 + rr)*64 + w*16 + arow] = accs[rr];
    __syncthreads();                                   // bar4: gates ready

    // elementwise LSTM cell; h store = packed relaxed agent atomics
    {
      float gi = gatesLds[er*64 +  0 + ec] + bi;
      float gf = gatesLds[er*64 + 16 + ec] + bff;
      float go = gatesLds[er*64 + 32 + ec] + bo;
      float gc = gatesLds[er*64 + 48 + ec] + bc;
      float ig = sigm(gi), fg = sigm(gf), og = sigm(go), ct = tanh_f(gc);
      cstate = fg*cstate + ig*ct;
      hout = og * tanh_f(cstate);
      unsigned hb = (unsigned)f2bf(hout);
      unsigned ob = __shfl_xor(hb, 1);                 // partner col (ec^1)
      if ((tid & 1) == 0){
        unsigned val = hb | (ob << 16);
        unsigned idx = (unsigned)((((t+1)&1)*NG + g)*GR + er)*256u
                     + (unsigned)(s*8 + (ec>>1));
        __hip_atomic_store(hbuf32 + idx, val, __ATOMIC_RELAXED,
                           __HIP_MEMORY_SCOPE_AGENT);
      }
    }

    // overlap next x staging with the h-store drain window
    if (t + 1 < SEQ) STAGE_X(t+1);

    __syncthreads();            // bar5: h stores vmcnt-drained (ack'd at LLC)

    // release flag: plain relaxed store AFTER the drain — no fence needed
    if (tid == 0)
      __hip_atomic_store(&gflags[s*32], (unsigned)(t+1),
                         __ATOMIC_RELAXED, __HIP_MEMORY_SCOPE_AGENT);
  }

  out[(size_t)(g*GR + er)*HID + s*SC + ec] = hout;
#undef GEMM_STEP
#undef STAGE_X
}

extern "C" void kernel_launch(void* const* d_in, const int* in_sizes, int n_in,
                              void* d_out, int out_size, void* d_ws, size_t ws_size,
                              hipStream_t stream)
{
  (void)in_sizes; (void)n_in; (void)out_size;
  if (ws_size < (size_t)WS_NEED) return;

  const float* x  = (const float*)d_in[0];
  const float* W0 = (const float*)d_in[1];
  const float* W1 = (const float*)d_in[2];
  const float* W2 = (const float*)d_in[3];
  const float* W3 = (const float*)d_in[4];
  const float* U0 = (const float*)d_in[5];
  const float* U1 = (const float*)d_in[6];
  const float* U2 = (const float*)d_in[7];
  const float* U3 = (const float*)d_in[8];
  const float* b0 = (const float*)d_in[9];
  const float* b1 = (const float*)d_in[10];
  const float* b2 = (const float*)d_in[11];
  const float* b3 = (const float*)d_in[12];
  float* out = (float*)d_out;

  unsigned* flags  = (unsigned*)d_ws;
  unsigned* hbuf32 = (unsigned*)((char*)d_ws + WS_FLAG_BYTES);

  const int n4 = WS_NEED / 16;
  zero_ws_kernel<<<dim3((n4 + 255)/256), dim3(256), 0, stream>>>((uint4*)d_ws, n4);
  lstm_persistent<<<dim3(NWG), dim3(NTHR), 0, stream>>>(
      x, W0,W1,W2,W3, U0,U1,U2,U3, b0,b1,b2,b3, out, flags, hbuf32);
}